// Round 9
// baseline (531.910 us; speedup 1.0000x reference)
//
#include <hip/hip_runtime.h>
#include <math.h>

#define NB 32
#define M 2048
#define N 1536
#define NORD 6

// ---- output offsets (flat fp32, reference return order) ----
#define OFF_COEFFS 0
#define OFF_RHS    49152
#define OFF_NSX    57344
#define OFF_NSY    57824
#define OFF_ATA    58304
#define OFF_ATPRHS 75555776
#define OFF_D      75604928
#define OFF_L      75654080
#define OFF_U      151151552
#define SMALL_TOTAL 58304

typedef short short8v __attribute__((ext_vector_type(8)));
typedef float f32x4 __attribute__((ext_vector_type(4)));

__device__ __forceinline__ void gload16(const void* g, void* l) {
    __builtin_amdgcn_global_load_lds(
        (const __attribute__((address_space(1))) void*)g,
        (__attribute__((address_space(3))) void*)l, 16, 0, 0);
}

__device__ __forceinline__ uint rtn_bf16(float x) {
    uint u = __float_as_uint(x);
    return (u + 0x7fffu + ((u >> 16) & 1u)) >> 16;   // round-to-nearest-even bf16
}

// nontemporal stores (round-5: -57us confirmed win)
__device__ __forceinline__ void nts(float v, float* p) {
    __builtin_nontemporal_store(v, p);
}
__device__ __forceinline__ void nts4(f32x4 v, float* p) {
    __builtin_nontemporal_store(v, (f32x4*)p);
}

// ---------------- small stuff: downsample coeffs/rhs, pair-sum steps ----------------
__global__ void small_kernel(const float* __restrict__ coeffs,
                             const float* __restrict__ rhs,
                             const float* __restrict__ sx,
                             const float* __restrict__ sy,
                             float* __restrict__ out) {
    int idx = blockIdx.x * blockDim.x + threadIdx.x;
    if (idx >= SMALL_TOTAL) return;
    const float scale = 31.0f / 15.0f;  // align_corners=True, 32 -> 16
    if (idx < 49152) {
        int b = idx / 1536;
        int rem = idx % 1536;
        int gp = rem / 6;
        int o  = rem % 6;
        int yy = gp / 16, xx = gp % 16;
        float py = (float)yy * scale;
        int ly = (int)floorf(py); if (ly > 30) ly = 30;
        float wy = py - (float)ly;
        float px = (float)xx * scale;
        int lx = (int)floorf(px); if (lx > 30) lx = 30;
        float wx = px - (float)lx;
        const float* base = coeffs + (size_t)b * 1024 * NORD;
        float v00 = base[(ly * 32 + lx) * NORD + o];
        float v01 = base[(ly * 32 + lx + 1) * NORD + o];
        float v10 = base[((ly + 1) * 32 + lx) * NORD + o];
        float v11 = base[((ly + 1) * 32 + lx + 1) * NORD + o];
        float a  = v00 * (1.0f - wy) + v10 * wy;
        float bb = v01 * (1.0f - wy) + v11 * wy;
        out[OFF_COEFFS + idx] = a * (1.0f - wx) + bb * wx;
    } else if (idx < 57344) {
        int j = idx - 49152;
        int b = j / 256;
        int gp = j % 256;
        int yy = gp / 16, xx = gp % 16;
        float py = (float)yy * scale;
        int ly = (int)floorf(py); if (ly > 30) ly = 30;
        float wy = py - (float)ly;
        float px = (float)xx * scale;
        int lx = (int)floorf(px); if (lx > 30) lx = 30;
        float wx = px - (float)lx;
        const float* base = rhs + (size_t)b * 1024;
        float v00 = base[ly * 32 + lx];
        float v01 = base[ly * 32 + lx + 1];
        float v10 = base[(ly + 1) * 32 + lx];
        float v11 = base[(ly + 1) * 32 + lx + 1];
        float a  = v00 * (1.0f - wy) + v10 * wy;
        float bb = v01 * (1.0f - wy) + v11 * wy;
        out[OFF_RHS + j] = a * (1.0f - wx) + bb * wx;
    } else if (idx < 57824) {
        int j = idx - 57344;
        int b = j / 15, k = j % 15;
        out[OFF_NSX + j] = sx[b * 31 + 2 * k] + sx[b * 31 + 2 * k + 1];
    } else {
        int j = idx - 57824;
        int b = j / 15, k = j % 15;
        out[OFF_NSY + j] = sy[b * 31 + 2 * k] + sy[b * 31 + 2 * k + 1];
    }
}

// ---------------- split A -> RTN bf16 (granule layout) + partial AtPrhs/D ----------------
// Ahi layout: [b][oct=m/8][col][8] ushort  (16B granule per (oct,col))
__global__ __launch_bounds__(256) void split_kernel(const float* __restrict__ A,
                                                    const float* __restrict__ Arhs,
                                                    ushort* __restrict__ Ahi,
                                                    float2* __restrict__ part) {
    int bid = blockIdx.x;
    int q  = bid & 3;
    int cb = (bid >> 2) % 6;
    int b  = bid / 24;
    int t  = threadIdx.x;
    int col = cb * 256 + t;
    const float* Ab = A + (size_t)b * M * N;
    const float* rb = Arhs + (size_t)b * M;
    uint4* Hp = (uint4*)Ahi;
    float s1 = 0.0f, s2 = 0.0f;
    for (int oct = q * 64; oct < q * 64 + 64; ++oct) {
        uint hw[4];
#pragma unroll
        for (int j = 0; j < 4; ++j) {
            float a0 = Ab[(size_t)(oct * 8 + 2 * j) * N + col];
            float a1 = Ab[(size_t)(oct * 8 + 2 * j + 1) * N + col];
            float r0 = rb[oct * 8 + 2 * j];
            float r1 = rb[oct * 8 + 2 * j + 1];
            s1 = fmaf(a0, r0, s1); s1 = fmaf(a1, r1, s1);
            s2 = fmaf(a0, a0, s2); s2 = fmaf(a1, a1, s2);
            hw[j] = rtn_bf16(a0) | (rtn_bf16(a1) << 16);
        }
        Hp[(size_t)(b * 256 + oct) * N + col] = make_uint4(hw[0], hw[1], hw[2], hw[3]);
    }
    part[(size_t)q * (NB * 6 * 256) + (size_t)(b * 6 + cb) * 256 + t] = make_float2(s1, s2);
}

__global__ __launch_bounds__(256) void reduce_kernel(const float2* __restrict__ part,
                                                     float* __restrict__ out) {
    int idx = blockIdx.x * 256 + threadIdx.x;   // 0..49151 == b*N + col
    float s1 = 0.0f, s2 = 0.0f;
#pragma unroll
    for (int q = 0; q < 4; ++q) {
        float2 p = part[(size_t)q * (NB * 6 * 256) + idx];
        s1 += p.x; s2 += p.y;
    }
    out[OFF_ATPRHS + idx] = s1;
    out[OFF_D + idx] = s2;
}

// ---------------- 8-phase bf16 MFMA SYRK (m201 geometry, SYRK-adapted) ----------------
// 256x256 tile, 8 waves (2Mx4N), wave-tile 128x64, BK=64 (2 x K32), 2 K-tiles/iter.
// LDS 128KB: [buf 2][arr A/B][oct 8][col 256][8]. Per phase: {4A(+4B even) ds_reads |
// 1 stage unit (2 gloads)} -> barrier -> lgkmcnt(0) -> 16 MFMA -> vmcnt(8) odd ends -> barrier.
#define SYRK8_BLOCKS (NB * 21)   // 672

__global__ __launch_bounds__(512, 2) void syrk8_kernel(const ushort* __restrict__ Ahi,
                                                       float* __restrict__ out) {
    __shared__ ushort lds[2][2][8 * 256 * 8];   // 128 KB

    int bid = blockIdx.x;
    int swz = (bid % 8) * (SYRK8_BLOCKS / 8) + bid / 8;   // XCD-chunked, bijective (672%8==0)
    int b  = swz / 21;
    int pp = swz % 21;
    int ti = 0;
    while ((ti + 1) * (ti + 2) / 2 <= pp) ++ti;
    int tj = pp - ti * (ti + 1) / 2;
    bool diag = (ti == tj);
    int i0 = ti * 256, j0 = tj * 256;             // diag: j0 == i0 (B staged as copy; uniform)

    int t = threadIdx.x, w = t >> 6, l = t & 63;
    int wr = w >> 2, wc = w & 3;                  // 2 x 4 wave grid
    int lc = l & 15, lg = l >> 4;

    const ushort* base = Ahi + (size_t)b * 256 * N * 8;

    f32x4 acc[8][4];
#pragma unroll
    for (int i = 0; i < 8; ++i)
#pragma unroll
        for (int j = 0; j < 4; ++j)
#pragma unroll
            for (int k = 0; k < 4; ++k) acc[i][j][k] = 0.0f;

    // stage unit n (n=0..127): kt=n>>2 into buf[kt&1]; u=n&3: arr=u&1 (A/B), h=u>>1 (K-half)
    int oc0 = t >> 8;          // 0/1
    int scol = t & 255;
    auto stage_unit = [&](int n) {
        int kt = n >> 2, u = n & 3;
        int arr = u & 1, h = u >> 1;
        int colb = arr ? j0 : i0;
        ushort* reg = &lds[kt & 1][arr][0];
#pragma unroll
        for (int c = 0; c < 2; ++c) {
            int oct = h * 4 + c * 2 + oc0;
            gload16(base + ((size_t)(kt * 8 + oct) * N + colb + scol) * 8,
                    reg + (size_t)(oct * 256 + scol) * 8);
        }
    };

    // prologue: kt0 + kt1 fully staged (8 units = 16 loads); need kt0 K-half0 (A+B) landed
    for (int n = 0; n < 8; ++n) stage_unit(n);
    asm volatile("s_waitcnt vmcnt(12)" ::: "memory");
    __builtin_amdgcn_s_barrier();

    for (int it = 0; it < 16; ++it) {
        short8v Bv[4];
#pragma unroll
        for (int p = 0; p < 8; ++p) {
            const int buf  = p >> 2;          // which K-tile buffer
            const int ksub = (p >> 1) & 1;    // K-half (octs 4*ksub..4*ksub+3)
            const int ch   = p & 1;           // C-half (ai 0..3 or 4..7)
            const ushort* Areg = &lds[buf][0][0];
            const ushort* Breg = &lds[buf][1][0];

            short8v Av[4];
#pragma unroll
            for (int aif = 0; aif < 4; ++aif) {
                int ai = ch * 4 + aif;
                Av[aif] = *(const short8v*)
                    &Areg[(size_t)((ksub * 4 + lg) * 256 + wr * 128 + ai * 16 + lc) * 8];
            }
            if (ch == 0) {
#pragma unroll
                for (int bj = 0; bj < 4; ++bj)
                    Bv[bj] = *(const short8v*)
                        &Breg[(size_t)((ksub * 4 + lg) * 256 + wc * 64 + bj * 16 + lc) * 8];
            }

            int g = it * 8 + p;               // global phase; stage slot g -> unit g+6
            if (g >= 2 && g <= 121) stage_unit(g + 6);

            asm volatile("" ::: "memory");
            __builtin_amdgcn_s_barrier();                 // reads+stage issued by all waves
            asm volatile("s_waitcnt lgkmcnt(0)" ::: "memory");
            __builtin_amdgcn_sched_barrier(0);            // rule #18

            __builtin_amdgcn_s_setprio(1);
#pragma unroll
            for (int aif = 0; aif < 4; ++aif)
#pragma unroll
                for (int bj = 0; bj < 4; ++bj)
                    acc[ch * 4 + aif][bj] = __builtin_amdgcn_mfma_f32_16x16x32_bf16(
                        Av[aif], Bv[bj], acc[ch * 4 + aif][bj], 0, 0, 0);
            __builtin_amdgcn_s_setprio(0);

            // counted waits only at odd-phase ends (next phase consumes fresh halves)
            if (p == 1) {
                if (it == 15) asm volatile("s_waitcnt vmcnt(4)" ::: "memory");
                else          asm volatile("s_waitcnt vmcnt(8)" ::: "memory");
            } else if (p == 3 || p == 5) {
                if (it == 15) asm volatile("s_waitcnt vmcnt(0)" ::: "memory");
                else          asm volatile("s_waitcnt vmcnt(8)" ::: "memory");
            } else if (p == 7) {
                if (it != 15) asm volatile("s_waitcnt vmcnt(8)" ::: "memory");
            }
            asm volatile("" ::: "memory");
            __builtin_amdgcn_s_barrier();                 // phase end: regions rotate
        }
    }

    float* AtA = out + OFF_ATA + (size_t)b * N * N;
    float* Lo  = out + OFF_L   + (size_t)b * N * N;
    float* Up  = out + OFF_U   + (size_t)b * N * N;

#pragma unroll
    for (int ai = 0; ai < 8; ++ai) {
        int gi0 = i0 + wr * 128 + ai * 16 + lg * 4;
#pragma unroll
        for (int bj = 0; bj < 4; ++bj) {
            int gj = j0 + wc * 64 + bj * 16 + lc;
#pragma unroll
            for (int r = 0; r < 4; ++r) {
                int gi = gi0 + r;
                float v = acc[ai][bj][r];
                size_t o = (size_t)gi * N + gj;
                nts(v, AtA + o);
                nts((gj <= gi) ? v : 0.0f, Lo + o);
                nts((gj >  gi) ? v : 0.0f, Up + o);
            }
            if (!diag) {                        // mirror: float4 over r (contiguous gi)
                f32x4 va = acc[ai][bj], vl, vu;
#pragma unroll
                for (int r = 0; r < 4; ++r) {
                    int gi = gi0 + r;
                    vl[r] = (gi <= gj) ? va[r] : 0.0f;
                    vu[r] = (gi >  gj) ? va[r] : 0.0f;
                }
                size_t om = (size_t)gj * N + gi0;
                nts4(va, AtA + om);
                nts4(vl, Lo  + om);
                nts4(vu, Up  + om);
            }
        }
    }
}

// ---------------- fp32 fallback (round-1, known-good) ----------------
__global__ __launch_bounds__(256) void atp_d_kernel(const float* __restrict__ A,
                                                    const float* __restrict__ Arhs,
                                                    float* __restrict__ out) {
    int b  = blockIdx.x / 6;
    int cb = blockIdx.x % 6;
    int col = cb * 256 + threadIdx.x;
    const float* Ab = A + (size_t)b * M * N;
    const float* rb = Arhs + (size_t)b * M;
    float s1 = 0.0f, s2 = 0.0f;
#pragma unroll 4
    for (int m = 0; m < M; ++m) {
        float a = Ab[(size_t)m * N + col];
        float r = rb[m];
        s1 = fmaf(a, r, s1);
        s2 = fmaf(a, a, s2);
    }
    out[OFF_ATPRHS + b * N + col] = s1;
    out[OFF_D      + b * N + col] = s2;
}

#define BM 128
#define BK 16
#define NPAIRS 78

__global__ __launch_bounds__(256, 2) void syrk_kernel(const float* __restrict__ A,
                                                      float* __restrict__ out) {
    __shared__ float As[BK][BM];
    __shared__ float Bs[BK][BM];

    int bid = blockIdx.x;
    int b = bid / NPAIRS;
    int p = bid % NPAIRS;
    int ti = (int)((sqrtf(8.0f * (float)p + 1.0f) - 1.0f) * 0.5f);
    while ((ti + 1) * (ti + 2) / 2 <= p) ++ti;
    while (ti * (ti + 1) / 2 > p) --ti;
    int tj = p - ti * (ti + 1) / 2;
    int i0 = ti * BM, j0 = tj * BM;

    const float* Ab = A + (size_t)b * M * N;
    int t = threadIdx.x;
    int tx = t % 16, ty = t / 16;
    int lcv = (t % 32) * 4;
    int lk = t / 32;

    float acc[2][4][2][4] = {};

    for (int m0 = 0; m0 < M; m0 += BK) {
        const float* pa = Ab + (size_t)(m0 + lk) * N;
        float4 a0 = *(const float4*)(pa + i0 + lcv);
        float4 a1 = *(const float4*)(pa + (size_t)8 * N + i0 + lcv);
        float4 b0 = *(const float4*)(pa + j0 + lcv);
        float4 b1 = *(const float4*)(pa + (size_t)8 * N + j0 + lcv);
        *(float4*)&As[lk][lcv]     = a0;
        *(float4*)&As[lk + 8][lcv] = a1;
        *(float4*)&Bs[lk][lcv]     = b0;
        *(float4*)&Bs[lk + 8][lcv] = b1;
        __syncthreads();
#pragma unroll
        for (int kk = 0; kk < BK; ++kk) {
            float ar[2][4], br[2][4];
            *(float4*)&ar[0][0] = *(const float4*)&As[kk][ty * 4];
            *(float4*)&ar[1][0] = *(const float4*)&As[kk][64 + ty * 4];
            *(float4*)&br[0][0] = *(const float4*)&Bs[kk][tx * 4];
            *(float4*)&br[1][0] = *(const float4*)&Bs[kk][64 + tx * 4];
#pragma unroll
            for (int rh = 0; rh < 2; ++rh)
#pragma unroll
                for (int r = 0; r < 4; ++r)
#pragma unroll
                    for (int ch = 0; ch < 2; ++ch)
#pragma unroll
                        for (int c = 0; c < 4; ++c)
                            acc[rh][r][ch][c] = fmaf(ar[rh][r], br[ch][c], acc[rh][r][ch][c]);
        }
        __syncthreads();
    }

    float* AtA = out + OFF_ATA + (size_t)b * N * N;
    float* L   = out + OFF_L   + (size_t)b * N * N;
    float* U   = out + OFF_U   + (size_t)b * N * N;

#pragma unroll
    for (int rh = 0; rh < 2; ++rh)
#pragma unroll
        for (int r = 0; r < 4; ++r) {
            int gi = i0 + rh * 64 + ty * 4 + r;
#pragma unroll
            for (int ch = 0; ch < 2; ++ch) {
                int gjb = j0 + ch * 64 + tx * 4;
                float ta[4], tl[4], tu[4];
#pragma unroll
                for (int c = 0; c < 4; ++c) {
                    int gj = gjb + c;
                    float v = acc[rh][r][ch][c];
                    ta[c] = v;
                    tl[c] = (gj <= gi) ? v : 0.0f;
                    tu[c] = (gj >  gi) ? v : 0.0f;
                }
                size_t o = (size_t)gi * N + gjb;
                *(float4*)(AtA + o) = *(float4*)ta;
                *(float4*)(L   + o) = *(float4*)tl;
                *(float4*)(U   + o) = *(float4*)tu;
            }
        }

    if (ti != tj) {
#pragma unroll
        for (int ch = 0; ch < 2; ++ch)
#pragma unroll
            for (int c = 0; c < 4; ++c) {
                int gj = j0 + ch * 64 + tx * 4 + c;
#pragma unroll
                for (int rh = 0; rh < 2; ++rh) {
                    int gib = i0 + rh * 64 + ty * 4;
                    float ta[4], tl[4], tu[4];
#pragma unroll
                    for (int r = 0; r < 4; ++r) {
                        int gi = gib + r;
                        float v = acc[rh][r][ch][c];
                        ta[r] = v;
                        tl[r] = (gi <= gj) ? v : 0.0f;
                        tu[r] = (gi >  gj) ? v : 0.0f;
                    }
                    size_t o = (size_t)gj * N + gib;
                    *(float4*)(AtA + o) = *(float4*)ta;
                    *(float4*)(L   + o) = *(float4*)tl;
                    *(float4*)(U   + o) = *(float4*)tu;
                }
            }
    }
}

extern "C" void kernel_launch(void* const* d_in, const int* in_sizes, int n_in,
                              void* d_out, int out_size, void* d_ws, size_t ws_size,
                              hipStream_t stream) {
    const float* coeffs = (const float*)d_in[0];
    const float* rhs    = (const float*)d_in[1];
    const float* sx     = (const float*)d_in[2];
    const float* sy     = (const float*)d_in[3];
    const float* A      = (const float*)d_in[4];
    const float* Arhs   = (const float*)d_in[5];
    float* out = (float*)d_out;

    small_kernel<<<(SMALL_TOTAL + 255) / 256, 256, 0, stream>>>(coeffs, rhs, sx, sy, out);

    const size_t hi_bytes   = (size_t)NB * M * N * sizeof(ushort);      // 201,326,592
    const size_t part_bytes = (size_t)4 * NB * 6 * 256 * sizeof(float2); // 1,572,864
    if (ws_size >= hi_bytes + part_bytes) {
        ushort* Ahi  = (ushort*)d_ws;
        float2* part = (float2*)((char*)d_ws + hi_bytes);
        split_kernel<<<768, 256, 0, stream>>>(A, Arhs, Ahi, part);
        reduce_kernel<<<192, 256, 0, stream>>>(part, out);
        syrk8_kernel<<<SYRK8_BLOCKS, 512, 0, stream>>>(Ahi, out);
    } else {
        atp_d_kernel<<<NB * 6, 256, 0, stream>>>(A, Arhs, out);
        syrk_kernel<<<NB * NPAIRS, 256, 0, stream>>>(A, out);
    }
}